// Round 1
// baseline (471.000 us; speedup 1.0000x reference)
//
#include <hip/hip_runtime.h>
#include <hip/hip_bf16.h>
#include <stdint.h>

#define BSZ   8192
#define D_IN  4096
#define D_OUT 4096
#define NM    128   // 8192/64 m-blocks
#define NK    64    // 4096/64 k-blocks

typedef __bf16 bf16x8 __attribute__((ext_vector_type(8)));
typedef float  f32x4  __attribute__((ext_vector_type(4)));
typedef unsigned short ushort_t;

__device__ __forceinline__ ushort_t f2bf(float f) {
  union { __hip_bfloat16 h; ushort_t u; } c;
  c.h = __float2bfloat16(f);
  return c.u;
}

__device__ __forceinline__ bf16x8 ld_frag(const ushort_t* p) {
  union { uint4 u; bf16x8 b; } cv;
  cv.u = *(const uint4*)p;
  return cv.b;
}

__device__ __forceinline__ void glds16(const ushort_t* g, ushort_t* l) {
  __builtin_amdgcn_global_load_lds(
      (const __attribute__((address_space(1))) unsigned int*)g,
      (__attribute__((address_space(3))) unsigned int*)l,
      16, 0, 0);
}

// ---------------------------------------------------------------------------
// Kernel A: per 64x64 block -> fp64 abs-sum -> mask; write x as bf16 (zeroed
// when inactive). One workgroup (256 thr) per block: 16 floats/thread.
// ---------------------------------------------------------------------------
__global__ __launch_bounds__(256) void mask_cast_kernel(
    const float* __restrict__ x, ushort_t* __restrict__ xb,
    int* __restrict__ mask) {
  const int kblk = blockIdx.x;   // 0..63
  const int mblk = blockIdx.y;   // 0..127
  const int tid  = threadIdx.x;
  const size_t row0 = (size_t)mblk * 64;
  const int    col0 = kblk * 64;

  float4 v[4];
  double s = 0.0;
#pragma unroll
  for (int i = 0; i < 4; ++i) {
    int j = i * 256 + tid;       // flat float4 index in 64x16 grid
    int r = j >> 4;              // row 0..63
    int c = (j & 15) * 4;        // col 0..60
    v[i] = *(const float4*)(x + (row0 + r) * D_IN + col0 + c);
    s += (double)fabsf(v[i].x) + (double)fabsf(v[i].y) +
         (double)fabsf(v[i].z) + (double)fabsf(v[i].w);
  }

  __shared__ double red[256];
  __shared__ int mflag;
  red[tid] = s;
  __syncthreads();
  for (int off = 128; off > 0; off >>= 1) {
    if (tid < off) red[tid] += red[tid + off];
    __syncthreads();
  }
  if (tid == 0) {
    float avg = (float)(red[0] * (1.0 / 4096.0));
    int m = (avg > 0.8f) ? 1 : 0;
    mflag = m;
    mask[mblk * NK + kblk] = m;
  }
  __syncthreads();
  const int act = mflag;

#pragma unroll
  for (int i = 0; i < 4; ++i) {
    int j = i * 256 + tid;
    int r = j >> 4;
    int c = (j & 15) * 4;
    ushort_t o0 = 0, o1 = 0, o2 = 0, o3 = 0;
    if (act) {
      o0 = f2bf(v[i].x); o1 = f2bf(v[i].y);
      o2 = f2bf(v[i].z); o3 = f2bf(v[i].w);
    }
    ushort4 o = make_ushort4(o0, o1, o2, o3);
    *(ushort4*)(xb + (row0 + r) * D_IN + col0 + c) = o;
  }
}

// ---------------------------------------------------------------------------
// Kernel B: w[k][n] fp32 -> wT[n][k] bf16 (LDS 64x64 tile transpose).
// ---------------------------------------------------------------------------
__global__ __launch_bounds__(256) void wcast_transpose_kernel(
    const float* __restrict__ w, ushort_t* __restrict__ wT) {
  const int ntile = blockIdx.x;  // 0..63
  const int ktile = blockIdx.y;  // 0..63
  const int tid   = threadIdx.x;
  const int k0 = ktile * 64, n0 = ntile * 64;

  __shared__ ushort_t t[64][65];  // +1 pad breaks transpose bank conflicts

#pragma unroll
  for (int i = 0; i < 4; ++i) {
    int j = i * 256 + tid;
    int r = j >> 4;              // k within tile
    int c = (j & 15) * 4;        // n within tile
    float4 v = *(const float4*)(w + (size_t)(k0 + r) * D_OUT + n0 + c);
    t[r][c + 0] = f2bf(v.x);
    t[r][c + 1] = f2bf(v.y);
    t[r][c + 2] = f2bf(v.z);
    t[r][c + 3] = f2bf(v.w);
  }
  __syncthreads();
#pragma unroll
  for (int i = 0; i < 4; ++i) {
    int j = i * 256 + tid;
    int r = j >> 4;              // n within tile
    int c = (j & 15) * 4;        // k within tile
    ushort4 o = make_ushort4(t[c + 0][r], t[c + 1][r], t[c + 2][r], t[c + 3][r]);
    *(ushort4*)(wT + (size_t)(n0 + r) * D_IN + k0 + c) = o;
  }
}

// ---------------------------------------------------------------------------
// Kernel C: block-sparse bf16 MFMA GEMM.
// Tile: M=64 (mask granularity), N=256, BK=64. 4 waves; wave w computes a
// 64x64 output (4x4 frags of 16x16x32). Skips inactive k-blocks via a
// compacted LDS list (uniform control flow around barriers).
// ---------------------------------------------------------------------------
__global__ __launch_bounds__(256) void bsp_gemm_kernel(
    const ushort_t* __restrict__ xb, const ushort_t* __restrict__ wT,
    const int* __restrict__ mask, float* __restrict__ out) {
  const int ntile = blockIdx.x;  // 0..15
  const int mblk  = blockIdx.y;  // 0..127
  const int tid   = threadIdx.x;
  const int lane  = tid & 63;
  const int wv    = tid >> 6;    // wave 0..3
  const int m0 = mblk * 64;
  const int n0 = ntile * 256;

  __shared__ ushort_t As[64 * 64];    // [m][k]  8 KB
  __shared__ ushort_t Bs[256 * 64];   // [n][k] 32 KB
  __shared__ int nact;
  __shared__ unsigned char klist[64];

  // build active-k list (uniform for the whole workgroup)
  const int* mrow = mask + mblk * NK;
  if (tid == 0) {
    int n = 0;
#pragma unroll
    for (int kb = 0; kb < NK; ++kb) {
      if (mrow[kb] != 0) klist[n++] = (unsigned char)kb;
    }
    nact = n;
  }
  __syncthreads();
  const int na = nact;

  f32x4 acc[4][4] = {};

  const int lr  = lane >> 3;        // 0..7 (row within 8-row staging group)
  const int lc  = (lane & 7) * 8;   // 0..56 (k col of 8-elem chunk)
  const int q   = lane >> 4;        // quad 0..3
  const int l15 = lane & 15;

  for (int ki = 0; ki < na; ++ki) {
    const int kb = klist[ki];
    const int k0 = kb * 64;

    // stage A: 64x64 bf16, 2 glds/wave (8 rows each)
#pragma unroll
    for (int t = 0; t < 2; ++t) {
      int rb = wv * 16 + t * 8;
      glds16(xb + (size_t)(m0 + rb + lr) * D_IN + k0 + lc, &As[rb * 64]);
    }
    // stage B: 256x64 bf16, 8 glds/wave
#pragma unroll
    for (int t = 0; t < 8; ++t) {
      int rb = wv * 64 + t * 8;
      glds16(wT + (size_t)(n0 + rb + lr) * D_IN + k0 + lc, &Bs[rb * 64]);
    }
    __syncthreads();

#pragma unroll
    for (int c = 0; c < 2; ++c) {
      bf16x8 a[4], b[4];
#pragma unroll
      for (int i = 0; i < 4; ++i)
        a[i] = ld_frag(&As[(i * 16 + l15) * 64 + c * 32 + q * 8]);
#pragma unroll
      for (int j = 0; j < 4; ++j)
        b[j] = ld_frag(&Bs[(wv * 64 + j * 16 + l15) * 64 + c * 32 + q * 8]);
#pragma unroll
      for (int i = 0; i < 4; ++i)
#pragma unroll
        for (int j = 0; j < 4; ++j)
          acc[i][j] = __builtin_amdgcn_mfma_f32_16x16x32_bf16(
              a[i], b[j], acc[i][j], 0, 0, 0);
    }
    __syncthreads();
  }

  // epilogue: C/D layout col=lane&15, row=quad*4+reg
#pragma unroll
  for (int i = 0; i < 4; ++i) {
#pragma unroll
    for (int j = 0; j < 4; ++j) {
#pragma unroll
      for (int r = 0; r < 4; ++r) {
        int row = m0 + i * 16 + q * 4 + r;
        int col = n0 + wv * 64 + j * 16 + l15;
        out[(size_t)row * D_OUT + col] = acc[i][j][r];
      }
    }
  }
}

// ---------------------------------------------------------------------------
extern "C" void kernel_launch(void* const* d_in, const int* in_sizes, int n_in,
                              void* d_out, int out_size, void* d_ws, size_t ws_size,
                              hipStream_t stream) {
  const float* x = (const float*)d_in[0];
  const float* w = (const float*)d_in[1];

  // workspace layout: x_bf16 (64 MB) | wT_bf16 (32 MB) | mask (32 KB)
  ushort_t* xb  = (ushort_t*)d_ws;
  ushort_t* wT  = (ushort_t*)((char*)d_ws + (size_t)BSZ * D_IN * 2);
  int*      msk = (int*)((char*)d_ws + (size_t)BSZ * D_IN * 2 + (size_t)D_IN * D_OUT * 2);
  float*    out = (float*)d_out;

  hipLaunchKernelGGL(mask_cast_kernel, dim3(NK, NM), dim3(256), 0, stream,
                     x, xb, msk);
  hipLaunchKernelGGL(wcast_transpose_kernel, dim3(64, 64), dim3(256), 0, stream,
                     w, wT);
  hipLaunchKernelGGL(bsp_gemm_kernel, dim3(D_OUT / 256, NM), dim3(256), 0, stream,
                     xb, wT, msk, out);
}

// Round 2
// 440.315 us; speedup vs baseline: 1.0697x; 1.0697x over previous
//
#include <hip/hip_runtime.h>
#include <hip/hip_bf16.h>
#include <stdint.h>

#define BSZ   8192
#define D_IN  4096
#define D_OUT 4096
#define NM    128   // 8192/64 m-blocks
#define NK    64    // 4096/64 k-blocks

typedef __bf16 bf16x8 __attribute__((ext_vector_type(8)));
typedef float  f32x4  __attribute__((ext_vector_type(4)));
typedef unsigned short ushort_t;

__device__ __forceinline__ ushort_t f2bf(float f) {
  union { __hip_bfloat16 h; ushort_t u; } c;
  c.h = __float2bfloat16(f);
  return c.u;
}

__device__ __forceinline__ bf16x8 ld_frag(const ushort_t* p) {
  union { uint4 u; bf16x8 b; } cv;
  cv.u = *(const uint4*)p;
  return cv.b;
}

__device__ __forceinline__ void glds16(const ushort_t* g, ushort_t* l) {
  __builtin_amdgcn_global_load_lds(
      (const __attribute__((address_space(1))) unsigned int*)g,
      (__attribute__((address_space(3))) unsigned int*)l,
      16, 0, 0);
}

// ---------------------------------------------------------------------------
// Kernel A: per 64x64 block -> fp64 abs-sum -> mask; write x as bf16 only for
// active blocks (inactive blocks are never read by the GEMM, which skips them).
// One workgroup (256 thr) per block: 16 floats/thread. Wave shuffle reduction.
// ---------------------------------------------------------------------------
__global__ __launch_bounds__(256) void mask_cast_kernel(
    const float* __restrict__ x, ushort_t* __restrict__ xb,
    int* __restrict__ mask) {
  const int kblk = blockIdx.x;   // 0..63
  const int mblk = blockIdx.y;   // 0..127
  const int tid  = threadIdx.x;
  const int lane = tid & 63;
  const int wv   = tid >> 6;
  const size_t row0 = (size_t)mblk * 64;
  const int    col0 = kblk * 64;

  float4 v[4];
  double s = 0.0;
#pragma unroll
  for (int i = 0; i < 4; ++i) {
    int j = i * 256 + tid;       // flat float4 index in 64x16 grid
    int r = j >> 4;              // row 0..63
    int c = (j & 15) * 4;        // col 0..60
    v[i] = *(const float4*)(x + (row0 + r) * D_IN + col0 + c);
    s += (double)fabsf(v[i].x) + (double)fabsf(v[i].y) +
         (double)fabsf(v[i].z) + (double)fabsf(v[i].w);
  }

  // wave-level butterfly reduction of the double sum (no barriers)
#pragma unroll
  for (int off = 32; off > 0; off >>= 1) {
    union { double d; int i2[2]; } u;
    u.d = s;
    u.i2[0] = __shfl_xor(u.i2[0], off, 64);
    u.i2[1] = __shfl_xor(u.i2[1], off, 64);
    s += u.d;
  }

  __shared__ double wsum[4];
  __shared__ int mflag;
  if (lane == 0) wsum[wv] = s;
  __syncthreads();
  if (tid == 0) {
    double tot = wsum[0] + wsum[1] + wsum[2] + wsum[3];
    float avg = (float)(tot * (1.0 / 4096.0));
    int m = (avg > 0.8f) ? 1 : 0;
    mflag = m;
    mask[mblk * NK + kblk] = m;
  }
  __syncthreads();

  if (mflag) {
#pragma unroll
    for (int i = 0; i < 4; ++i) {
      int j = i * 256 + tid;
      int r = j >> 4;
      int c = (j & 15) * 4;
      ushort4 o = make_ushort4(f2bf(v[i].x), f2bf(v[i].y),
                               f2bf(v[i].z), f2bf(v[i].w));
      *(ushort4*)(xb + (row0 + r) * D_IN + col0 + c) = o;
    }
  }
}

// ---------------------------------------------------------------------------
// Kernel B: w[k][n] fp32 -> wT[n][k] bf16 (LDS 64x64 tile transpose).
// ---------------------------------------------------------------------------
__global__ __launch_bounds__(256) void wcast_transpose_kernel(
    const float* __restrict__ w, ushort_t* __restrict__ wT) {
  const int ntile = blockIdx.x;  // 0..63
  const int ktile = blockIdx.y;  // 0..63
  const int tid   = threadIdx.x;
  const int k0 = ktile * 64, n0 = ntile * 64;

  __shared__ ushort_t t[64][65];  // +1 pad breaks transpose bank conflicts

#pragma unroll
  for (int i = 0; i < 4; ++i) {
    int j = i * 256 + tid;
    int r = j >> 4;              // k within tile
    int c = (j & 15) * 4;        // n within tile
    float4 v = *(const float4*)(w + (size_t)(k0 + r) * D_OUT + n0 + c);
    t[r][c + 0] = f2bf(v.x);
    t[r][c + 1] = f2bf(v.y);
    t[r][c + 2] = f2bf(v.z);
    t[r][c + 3] = f2bf(v.w);
  }
  __syncthreads();
#pragma unroll
  for (int i = 0; i < 4; ++i) {
    int j = i * 256 + tid;
    int r = j >> 4;              // n within tile
    int c = (j & 15) * 4;        // k within tile
    ushort4 o = make_ushort4(t[c + 0][r], t[c + 1][r], t[c + 2][r], t[c + 3][r]);
    *(ushort4*)(wT + (size_t)(n0 + r) * D_IN + k0 + c) = o;
  }
}

// ---------------------------------------------------------------------------
// Kernel C: block-sparse bf16 MFMA GEMM.
// Tile: M=64 (mask granularity), N=256, BK=64. 4 waves; wave w computes a
// 64x64 output (4x4 frags of 16x16x32). Skips inactive k-blocks via a
// compacted LDS list (uniform control flow around barriers).
//
// LDS layout is XOR-swizzled to kill bank conflicts: row stride is 128 B
// (= exactly 32 banks), so the natural layout put all 16 lanes of a
// fragment read on one 4-bank group (~8-16-way conflict, SQ_LDS_BANK_CONFLICT
// 4.1e7 in R1). global_load_lds forces LDS slot = lane order, but we choose
// WHICH global 16B chunk each lane fetches: lane l stages chunk
// (l&7)^(l>>3) of its row, so LDS slot s of row r holds global chunk
// s^(r&7). Fragment reads then address chunk (c*4+q)^(row&7): 16 lanes
// spread over 8 slots x 16B = all 32 banks, 2 lanes/bank = conflict-free.
// ---------------------------------------------------------------------------
__global__ __launch_bounds__(256) void bsp_gemm_kernel(
    const ushort_t* __restrict__ xb, const ushort_t* __restrict__ wT,
    const int* __restrict__ mask, float* __restrict__ out) {
  const int ntile = blockIdx.x;  // 0..15
  const int mblk  = blockIdx.y;  // 0..127
  const int tid   = threadIdx.x;
  const int lane  = tid & 63;
  const int wv    = tid >> 6;    // wave 0..3
  const int m0 = mblk * 64;
  const int n0 = ntile * 256;

  __shared__ ushort_t As[64 * 64];    // [m][k-chunk swizzled]  8 KB
  __shared__ ushort_t Bs[256 * 64];   // [n][k-chunk swizzled] 32 KB
  __shared__ int nact;
  __shared__ unsigned char klist[64];

  // build active-k list (uniform for the whole workgroup)
  const int* mrow = mask + mblk * NK;
  if (tid == 0) {
    int n = 0;
#pragma unroll
    for (int kb = 0; kb < NK; ++kb) {
      if (mrow[kb] != 0) klist[n++] = (unsigned char)kb;
    }
    nact = n;
  }
  __syncthreads();
  const int na = nact;

  f32x4 acc[4][4] = {};

  const int lr  = lane >> 3;                       // 0..7 row within 8-row group
  const int lcs = ((lane & 7) ^ (lane >> 3)) * 8;  // swizzled global chunk (ushorts)
  const int q   = lane >> 4;                       // quad 0..3
  const int l15 = lane & 15;
  const int sx  = l15 & 7;                         // row-phase for readback swizzle

  for (int ki = 0; ki < na; ++ki) {
    const int kb = klist[ki];
    const int k0 = kb * 64;

    // stage A: 64x64 bf16, 2 glds/wave (8 rows each)
#pragma unroll
    for (int t = 0; t < 2; ++t) {
      int rb = wv * 16 + t * 8;
      glds16(xb + (size_t)(m0 + rb + lr) * D_IN + k0 + lcs, &As[rb * 64]);
    }
    // stage B: 256x64 bf16, 8 glds/wave
#pragma unroll
    for (int t = 0; t < 8; ++t) {
      int rb = wv * 64 + t * 8;
      glds16(wT + (size_t)(n0 + rb + lr) * D_IN + k0 + lcs, &Bs[rb * 64]);
    }
    __syncthreads();

#pragma unroll
    for (int c = 0; c < 2; ++c) {
      const int sw = ((c * 4 + q) ^ sx) * 8;   // swizzled chunk offset (ushorts)
      bf16x8 a[4], b[4];
#pragma unroll
      for (int i = 0; i < 4; ++i)
        a[i] = ld_frag(&As[(i * 16 + l15) * 64 + sw]);
#pragma unroll
      for (int j = 0; j < 4; ++j)
        b[j] = ld_frag(&Bs[(wv * 64 + j * 16 + l15) * 64 + sw]);
#pragma unroll
      for (int i = 0; i < 4; ++i)
#pragma unroll
        for (int j = 0; j < 4; ++j)
          acc[i][j] = __builtin_amdgcn_mfma_f32_16x16x32_bf16(
              a[i], b[j], acc[i][j], 0, 0, 0);
    }
    __syncthreads();
  }

  // epilogue: C/D layout col=lane&15, row=quad*4+reg
#pragma unroll
  for (int i = 0; i < 4; ++i) {
#pragma unroll
    for (int j = 0; j < 4; ++j) {
#pragma unroll
      for (int r = 0; r < 4; ++r) {
        int row = m0 + i * 16 + q * 4 + r;
        int col = n0 + wv * 64 + j * 16 + l15;
        out[(size_t)row * D_OUT + col] = acc[i][j][r];
      }
    }
  }
}

// ---------------------------------------------------------------------------
extern "C" void kernel_launch(void* const* d_in, const int* in_sizes, int n_in,
                              void* d_out, int out_size, void* d_ws, size_t ws_size,
                              hipStream_t stream) {
  const float* x = (const float*)d_in[0];
  const float* w = (const float*)d_in[1];

  // workspace layout: x_bf16 (64 MB) | wT_bf16 (32 MB) | mask (32 KB)
  ushort_t* xb  = (ushort_t*)d_ws;
  ushort_t* wT  = (ushort_t*)((char*)d_ws + (size_t)BSZ * D_IN * 2);
  int*      msk = (int*)((char*)d_ws + (size_t)BSZ * D_IN * 2 + (size_t)D_IN * D_OUT * 2);
  float*    out = (float*)d_out;

  hipLaunchKernelGGL(mask_cast_kernel, dim3(NK, NM), dim3(256), 0, stream,
                     x, xb, msk);
  hipLaunchKernelGGL(wcast_transpose_kernel, dim3(64, 64), dim3(256), 0, stream,
                     w, wT);
  hipLaunchKernelGGL(bsp_gemm_kernel, dim3(D_OUT / 256, NM), dim3(256), 0, stream,
                     xb, wT, msk, out);
}